// Round 4
// baseline (314.991 us; speedup 1.0000x reference)
//
#include <hip/hip_runtime.h>

// MeanPoolAggregator: out[n] = W @ mean_k(features[neigh_idx[n,k]])
// (mean-then-project — exact by linearity; no workspace needed.)
//
// R3 (resubmit — R3 bench never acquired a GPU): latency-bound fix.
// 2000 blocks x 25 nodes (occupancy 8->~20 waves/CU), float4 gather
// (wave g owns k=4g..4g+3, full-row dwordx4 loads), block-cached indices.

#define N_NODES  50000
#define N_UNIQUE 100000
#define KNEI     16
#define HID      256
#define POOL     128

#define NBLOCKS  2000
#define NPB      25            // 2000 * 25 == 50000 exactly

__global__ __launch_bounds__(256) void fused_meanpool_kernel(
    const int*   __restrict__ idx,    // [N_NODES][KNEI] int32
    const float* __restrict__ feats,  // [N_UNIQUE][HID]
    const float* __restrict__ W,      // [POOL][HID]
    float* __restrict__ out)          // [N_NODES][POOL]
{
    __shared__ float4 part1[4][64];       // gather partials [kgroup][lane]  (4 KB)
    __shared__ float4 part2[8][32];       // proj partials  [ksl][og]        (4 KB)
    __shared__ int    idxc[NPB * KNEI];   // block's neighbor indices        (1.6 KB)

    const int tid  = threadIdx.x;
    const int wv   = tid >> 6;        // wave 0..3 -> k-group
    const int lane = tid & 63;
    const int og   = tid & 31;        // output group: p = og*4 .. og*4+3
    const int ksl  = tid >> 5;        // K-slice: h = ksl*32 .. ksl*32+31

    // ---- W slice into registers (once per block) ----
    float4 w[4][8];
#pragma unroll
    for (int e = 0; e < 4; ++e) {
        const float* wr = W + (size_t)(og * 4 + e) * HID + ksl * 32;
#pragma unroll
        for (int j4 = 0; j4 < 8; ++j4)
            w[e][j4] = *reinterpret_cast<const float4*>(wr + j4 * 4);
    }

    const int node0 = blockIdx.x * NPB;

    // ---- cache this block's indices (coalesced, once) ----
    for (int j = tid; j < NPB * KNEI; j += 256) {
        int v = idx[node0 * KNEI + j];
        idxc[j] = ((unsigned)v < (unsigned)N_UNIQUE) ? v : 0;  // crash-proof clamp
    }
    __syncthreads();

    for (int i = 0; i < NPB; ++i) {
        // ---- phase 1: gather. wave wv sums rows k=4wv..4wv+3; lane owns ch 4l..4l+3 ----
        const int kb = i * KNEI + wv * 4;
        const int r0 = idxc[kb + 0];
        const int r1 = idxc[kb + 1];
        const int r2 = idxc[kb + 2];
        const int r3 = idxc[kb + 3];
        const float4 v0 = reinterpret_cast<const float4*>(feats + (size_t)r0 * HID)[lane];
        const float4 v1 = reinterpret_cast<const float4*>(feats + (size_t)r1 * HID)[lane];
        const float4 v2 = reinterpret_cast<const float4*>(feats + (size_t)r2 * HID)[lane];
        const float4 v3 = reinterpret_cast<const float4*>(feats + (size_t)r3 * HID)[lane];
        float4 s;
        s.x = (v0.x + v1.x) + (v2.x + v3.x);
        s.y = (v0.y + v1.y) + (v2.y + v3.y);
        s.z = (v0.z + v1.z) + (v2.z + v3.z);
        s.w = (v0.w + v1.w) + (v2.w + v3.w);
        part1[wv][lane] = s;
        __syncthreads();

        // ---- phase 2: reduce 4 k-partials + project vs register W ----
        float4 acc = make_float4(0.f, 0.f, 0.f, 0.f);
#pragma unroll
        for (int j4 = 0; j4 < 8; ++j4) {
            const int fi = ksl * 8 + j4;              // float4 index into the 256-ch row
            const float4 a0 = part1[0][fi];           // uniform across 32-thread group
            const float4 a1 = part1[1][fi];           //  -> LDS broadcast, ~free
            const float4 a2 = part1[2][fi];
            const float4 a3 = part1[3][fi];
            float4 m4;
            m4.x = (a0.x + a1.x) + (a2.x + a3.x);
            m4.y = (a0.y + a1.y) + (a2.y + a3.y);
            m4.z = (a0.z + a1.z) + (a2.z + a3.z);
            m4.w = (a0.w + a1.w) + (a2.w + a3.w);
            acc.x = fmaf(w[0][j4].x, m4.x, acc.x);
            acc.x = fmaf(w[0][j4].y, m4.y, acc.x);
            acc.x = fmaf(w[0][j4].z, m4.z, acc.x);
            acc.x = fmaf(w[0][j4].w, m4.w, acc.x);
            acc.y = fmaf(w[1][j4].x, m4.x, acc.y);
            acc.y = fmaf(w[1][j4].y, m4.y, acc.y);
            acc.y = fmaf(w[1][j4].z, m4.z, acc.y);
            acc.y = fmaf(w[1][j4].w, m4.w, acc.y);
            acc.z = fmaf(w[2][j4].x, m4.x, acc.z);
            acc.z = fmaf(w[2][j4].y, m4.y, acc.z);
            acc.z = fmaf(w[2][j4].z, m4.z, acc.z);
            acc.z = fmaf(w[2][j4].w, m4.w, acc.z);
            acc.w = fmaf(w[3][j4].x, m4.x, acc.w);
            acc.w = fmaf(w[3][j4].y, m4.y, acc.w);
            acc.w = fmaf(w[3][j4].z, m4.z, acc.w);
            acc.w = fmaf(w[3][j4].w, m4.w, acc.w);
        }
        part2[ksl][og] = acc;
        __syncthreads();

        // ---- phase 3: reduce 8 K-slices, scale, store ----
        if (tid < 32) {
            float4 s3 = part2[0][tid];
#pragma unroll
            for (int k = 1; k < 8; ++k) {
                const float4 p4 = part2[k][tid];
                s3.x += p4.x; s3.y += p4.y; s3.z += p4.z; s3.w += p4.w;
            }
            const float inv = 1.f / (float)KNEI;
            s3.x *= inv; s3.y *= inv; s3.z *= inv; s3.w *= inv;
            *reinterpret_cast<float4*>(out + (size_t)(node0 + i) * POOL + tid * 4) = s3;
        }
        // no trailing barrier needed: part1 rewrites happen before the next
        // phase-1 barrier; part2 rewrites happen after it; idxc is read-only here.
    }
}

extern "C" void kernel_launch(void* const* d_in, const int* in_sizes, int n_in,
                              void* d_out, int out_size, void* d_ws, size_t ws_size,
                              hipStream_t stream) {
    const int*   idx   = (const int*)d_in[0];
    const float* feats = (const float*)d_in[1];
    const float* W     = (const float*)d_in[2];
    float* out = (float*)d_out;

    fused_meanpool_kernel<<<NBLOCKS, 256, 0, stream>>>(idx, feats, W, out);
}